// Round 1
// baseline (850.419 us; speedup 1.0000x reference)
//
#include <hip/hip_runtime.h>
#include <cstdint>

#define AS1 __attribute__((address_space(1)))
#define AS3 __attribute__((address_space(3)))

// Problem constants (fixed by setup_inputs)
constexpr int B  = 4;
constexpr int C  = 32;
constexpr int H  = 512;
constexpr int Wd = 960;
constexpr int Ht = H / 4;    // 128
constexpr int Wt = Wd / 4;   // 240
constexpr int HW = H * Wd;

constexpr int BLKX  = 256;        // x-pixels per block
constexpr int XMARG = 56;         // left margin: disp <= 48+1+slant(~1.5) -> taps >= x-52
constexpr int SELEM = BLKX + 64;  // 320 staged floats per channel (covers [x0-56, x0+263])
constexpr int CPH   = 16;         // channels per staging phase
constexpr int NPH   = C / CPH;    // 2 phases, one shared 20480 B buffer
constexpr int NCHUNK = (SELEM * CPH) / (BLKX * 4);   // 5 DMA chunks per phase

// out[b, k*16 + i*4 + j, ht, wt] = sum_c |fea_l[b,c,y,x] - warp(fea_r, disp_k)[b,c,y,x]|
__global__ __launch_bounds__(256, 7) void tile_warping_kernel(
    const float* __restrict__ tp,   // [B,3,Ht,Wt]
    const float* __restrict__ fl,   // [B,C,H,W]
    const float* __restrict__ fr,   // [B,C,H,W]
    float* __restrict__ out)        // [B,48,Ht,Wt]
{
    // 20480 B -> LDS allows exactly 8 blocks/CU (8*20480 = 160 KiB);
    // launch_bounds(256,7) caps VGPRs at 73 so VGPR-occupancy ~7 blocks.
    __shared__ float sm[SELEM * CPH];

    const int lane = threadIdx.x;
    const int x0 = blockIdx.x * BLKX;
    const int y  = blockIdx.y;
    const int b  = blockIdx.z;
    const int xstart = x0 - XMARG;

    const float* frrow = fr + ((size_t)b * C * H + y) * Wd;

    // ---- phase-0 stage issue ASAP (channels 0..15) ----
    // Linear LDS fill: dest = wave-uniform base + lane*16 B (required by
    // global_load_lds); clamped slots are never read.
    #pragma unroll
    for (int chunk = 0; chunk < NCHUNK; ++chunk) {
        int e   = chunk * (BLKX * 4) + lane * 4;   // element index in sm
        int ch  = e / SELEM;
        int off = e - ch * SELEM;
        int gx  = min(max(xstart + off, 0), Wd - 4);
        const float* gp = frrow + (size_t)ch * HW + gx;
        __builtin_amdgcn_global_load_lds((const AS1 float*)gp,
                                         (AS3 float*)(&sm[e]), 16, 0, 0);
    }

    // ---- per-thread setup (overlaps the stage latency) ----
    const int x   = x0 + lane;
    const bool act = (x < Wd);

    const int ht = y >> 2, ii = y & 3;
    const int wt = x >> 2, jj = x & 3;

    int   o0[3];
    float w[3], w1[3];
    bool  val[3];
    float s0 = 0.f, s1 = 0.f, s2 = 0.f;
    const float* flp = fl + ((size_t)b * C * H + y) * Wd + x;

    if (act) {
        const int tbase = ((b * 3) * Ht + ht) * Wt + wt;
        const float dv  = tp[tbase];
        const float dxv = tp[tbase + Ht * Wt];
        const float dyv = tp[tbase + 2 * Ht * Wt];

        const float oi = (float)ii - 1.5f;
        const float oj = (float)jj - 1.5f;

        #pragma unroll
        for (int k = 0; k < 3; ++k) {
            // Reference rounding order: ((d + disp_d) + oi*dy) + oj*dx
            float disp = ((dv + (float)(k - 1)) + oi * dyv) + oj * dxv;
            float xs = (float)x - disp;
            float ff = floorf(xs);
            w[k]  = xs - ff;
            w1[k] = 1.0f - w[k];
            int c0 = min(max((int)ff, 0), Wd - 1);
            o0[k]  = c0 - xstart;   // f1 slot o0+1: if c0==W-1 it's garbage but
                                    // w==0 or invalid there, and finite.
            val[k] = (xs >= 0.0f) && (xs <= (float)(Wd - 1));
        }
    } else {
        o0[0] = o0[1] = o0[2] = 0;
        w[0] = w[1] = w[2] = 0.f;
        w1[0] = w1[1] = w1[2] = 0.f;
        val[0] = val[1] = val[2] = false;
    }

    #pragma unroll
    for (int p = 0; p < NPH; ++p) {
        if (p) {
            __syncthreads();   // all waves done reading phase p-1 from sm
            #pragma unroll
            for (int chunk = 0; chunk < NCHUNK; ++chunk) {
                int e   = chunk * (BLKX * 4) + lane * 4;
                int ch  = e / SELEM;
                int off = e - ch * SELEM;
                int gx  = min(max(xstart + off, 0), Wd - 4);
                const float* gp = frrow + (size_t)(p * CPH + ch) * HW + gx;
                __builtin_amdgcn_global_load_lds((const AS1 float*)gp,
                                                 (AS3 float*)(&sm[e]), 16, 0, 0);
            }
        }

        // Prefetch this phase's fea_l values BEFORE the barrier: the
        // compiler's vmcnt(0) drain at __syncthreads completes them during
        // the staging wait -> compute loop has zero global-load stalls.
        float l[CPH];
        if (act) {
            #pragma unroll
            for (int c = 0; c < CPH; ++c)
                l[c] = flp[(size_t)(p * CPH + c) * HW];
        }

        __syncthreads();       // stage (and fea_l prefetch) complete

        if (act) {
            #pragma unroll
            for (int c = 0; c < CPH; ++c) {
                const float* bp = sm + c * SELEM;
                float f00 = bp[o0[0]], f01 = bp[o0[0] + 1];
                float f10 = bp[o0[1]], f11 = bp[o0[1] + 1];
                float f20 = bp[o0[2]], f21 = bp[o0[2] + 1];
                float wv0 = val[0] ? (f00 * w1[0] + f01 * w[0]) : 0.f;
                float wv1 = val[1] ? (f10 * w1[1] + f11 * w[1]) : 0.f;
                float wv2 = val[2] ? (f20 * w1[2] + f21 * w[2]) : 0.f;
                s0 += fabsf(l[c] - wv0);
                s1 += fabsf(l[c] - wv1);
                s2 += fabsf(l[c] - wv2);
            }
        }
    }

    if (act) {
        const int obase = ((b * 48) * Ht + ht) * Wt + wt;
        out[obase + (0 * 16 + ii * 4 + jj) * (Ht * Wt)] = s0;
        out[obase + (1 * 16 + ii * 4 + jj) * (Ht * Wt)] = s1;
        out[obase + (2 * 16 + ii * 4 + jj) * (Ht * Wt)] = s2;
    }
}

extern "C" void kernel_launch(void* const* d_in, const int* in_sizes, int n_in,
                              void* d_out, int out_size, void* d_ws, size_t ws_size,
                              hipStream_t stream) {
    const float* tp = (const float*)d_in[0];
    const float* fl = (const float*)d_in[1];
    const float* fr = (const float*)d_in[2];
    float* out = (float*)d_out;

    dim3 grid((Wd + BLKX - 1) / BLKX, H, B);   // (4, 512, 4)
    tile_warping_kernel<<<grid, 256, 0, stream>>>(tp, fl, fr, out);
}

// Round 2
// 495.058 us; speedup vs baseline: 1.7178x; 1.7178x over previous
//
#include <hip/hip_runtime.h>
#include <cstdint>

#define AS1 __attribute__((address_space(1)))
#define AS3 __attribute__((address_space(3)))

// Problem constants (fixed by setup_inputs)
constexpr int B  = 4;
constexpr int C  = 32;
constexpr int H  = 512;
constexpr int Wd = 960;
constexpr int Ht = H / 4;    // 128
constexpr int Wt = Wd / 4;   // 240
constexpr int HW = H * Wd;

constexpr int BLKX  = 256;        // x-pixels per block
constexpr int XMARG = 56;         // left margin: disp <= 48+1+slant(~1.5) -> taps >= x-52
constexpr int SELEM = BLKX + 64;  // 320 staged floats per channel (covers [x0-56, x0+263])
constexpr int CPH   = 16;         // channels per staging phase
constexpr int NPH   = C / CPH;    // 2 phases, one shared 20480 B buffer
constexpr int NCHUNK = (SELEM * CPH) / (BLKX * 4);   // 5 DMA chunks per phase

// out[b, k*16 + i*4 + j, ht, wt] = sum_c |fea_l[b,c,y,x] - warp(fea_r, disp_k)[b,c,y,x]|
//
// Register regime: launch_bounds(256,4) is the PROVEN allocation (round-0
// compiled to 52 VGPR, zero spill). Do NOT tighten the min-waves arg: forcing
// 7 waves/EU made the allocator spill everything to scratch (1.19 GB of
// scratch writes, 3x regression). Occupancy comes from VGPR<=64 (HW grants
// 8 waves/SIMD) + 20480 B LDS (exactly 8 blocks/CU).
__global__ __launch_bounds__(256, 4) void tile_warping_kernel(
    const float* __restrict__ tp,   // [B,3,Ht,Wt]
    const float* __restrict__ fl,   // [B,C,H,W]
    const float* __restrict__ fr,   // [B,C,H,W]
    float* __restrict__ out)        // [B,48,Ht,Wt]
{
    __shared__ float sm[SELEM * CPH];   // 20480 B -> 8 blocks/CU

    const int lane = threadIdx.x;
    const int x0 = blockIdx.x * BLKX;
    const int y  = blockIdx.y;
    const int b  = blockIdx.z;
    const int xstart = x0 - XMARG;

    const float* frrow = fr + ((size_t)b * C * H + y) * Wd;

    // ---- phase-0 stage issue ASAP (channels 0..15) ----
    // Linear LDS fill: dest = wave-uniform base + lane*16 B (required by
    // global_load_lds); clamped slots are never read.
    #pragma unroll
    for (int chunk = 0; chunk < NCHUNK; ++chunk) {
        int e   = chunk * (BLKX * 4) + lane * 4;   // element index in sm
        int ch  = e / SELEM;
        int off = e - ch * SELEM;
        int gx  = min(max(xstart + off, 0), Wd - 4);
        const float* gp = frrow + (size_t)ch * HW + gx;
        __builtin_amdgcn_global_load_lds((const AS1 float*)gp,
                                         (AS3 float*)(&sm[e]), 16, 0, 0);
    }

    // ---- per-thread setup (overlaps the stage latency) ----
    const int x   = x0 + lane;
    const bool act = (x < Wd);

    const int ht = y >> 2, ii = y & 3;
    const int wt = x >> 2, jj = x & 3;

    int   o0[3];
    float w[3], w1[3];
    bool  val[3];
    float s0 = 0.f, s1 = 0.f, s2 = 0.f;
    const float* flp = fl + ((size_t)b * C * H + y) * Wd + x;

    if (act) {
        const int tbase = ((b * 3) * Ht + ht) * Wt + wt;
        const float dv  = tp[tbase];
        const float dxv = tp[tbase + Ht * Wt];
        const float dyv = tp[tbase + 2 * Ht * Wt];

        const float oi = (float)ii - 1.5f;
        const float oj = (float)jj - 1.5f;

        #pragma unroll
        for (int k = 0; k < 3; ++k) {
            // Reference rounding order: ((d + disp_d) + oi*dy) + oj*dx
            float disp = ((dv + (float)(k - 1)) + oi * dyv) + oj * dxv;
            float xs = (float)x - disp;
            float ff = floorf(xs);
            w[k]  = xs - ff;
            w1[k] = 1.0f - w[k];
            int c0 = min(max((int)ff, 0), Wd - 1);
            o0[k]  = c0 - xstart;   // f1 slot o0+1: if c0==W-1 it's garbage but
                                    // w==0 or invalid there, and finite.
            val[k] = (xs >= 0.0f) && (xs <= (float)(Wd - 1));
        }
    }

    #pragma unroll
    for (int p = 0; p < NPH; ++p) {
        if (p) {
            __syncthreads();   // all waves done reading phase p-1 from sm
            #pragma unroll
            for (int chunk = 0; chunk < NCHUNK; ++chunk) {
                int e   = chunk * (BLKX * 4) + lane * 4;
                int ch  = e / SELEM;
                int off = e - ch * SELEM;
                int gx  = min(max(xstart + off, 0), Wd - 4);
                const float* gp = frrow + (size_t)(p * CPH + ch) * HW + gx;
                __builtin_amdgcn_global_load_lds((const AS1 float*)gp,
                                                 (AS3 float*)(&sm[e]), 16, 0, 0);
            }
        }

        __syncthreads();       // stage complete

        if (act) {
            // unroll 8: ~8 fea_l loads in flight per wave (was 4). Keeps
            // VGPR under the 64-reg occupancy step; no spill.
            #pragma unroll 8
            for (int c = 0; c < CPH; ++c) {
                float l = flp[(size_t)(p * CPH + c) * HW];
                const float* bp = sm + c * SELEM;
                float f00 = bp[o0[0]], f01 = bp[o0[0] + 1];
                float f10 = bp[o0[1]], f11 = bp[o0[1] + 1];
                float f20 = bp[o0[2]], f21 = bp[o0[2] + 1];
                float wv0 = val[0] ? (f00 * w1[0] + f01 * w[0]) : 0.f;
                float wv1 = val[1] ? (f10 * w1[1] + f11 * w[1]) : 0.f;
                float wv2 = val[2] ? (f20 * w1[2] + f21 * w[2]) : 0.f;
                s0 += fabsf(l - wv0);
                s1 += fabsf(l - wv1);
                s2 += fabsf(l - wv2);
            }
        }
    }

    if (act) {
        const int obase = ((b * 48) * Ht + ht) * Wt + wt;
        out[obase + (0 * 16 + ii * 4 + jj) * (Ht * Wt)] = s0;
        out[obase + (1 * 16 + ii * 4 + jj) * (Ht * Wt)] = s1;
        out[obase + (2 * 16 + ii * 4 + jj) * (Ht * Wt)] = s2;
    }
}

extern "C" void kernel_launch(void* const* d_in, const int* in_sizes, int n_in,
                              void* d_out, int out_size, void* d_ws, size_t ws_size,
                              hipStream_t stream) {
    const float* tp = (const float*)d_in[0];
    const float* fl = (const float*)d_in[1];
    const float* fr = (const float*)d_in[2];
    float* out = (float*)d_out;

    dim3 grid((Wd + BLKX - 1) / BLKX, H, B);   // (4, 512, 4)
    tile_warping_kernel<<<grid, 256, 0, stream>>>(tp, fl, fr, out);
}